// Round 6
// baseline (174.884 us; speedup 1.0000x reference)
//
#include <hip/hip_runtime.h>
#include <math.h>

#define B_   2
#define C_   256
#define C4_  64
#define H_   128
#define W_   128
#define HW_  (H_*W_)
#define G_   4
#define PX_  32                       // pixels per main block
#define NCH_ (W_/PX_)                 // 4 chunks per row
#define NBLK (B_*H_*NCH_)             // 1024 blocks

typedef float f4_t __attribute__((ext_vector_type(4)));

// ---------------------------------------------------------------------------
// prep body: fold W0 + BN + W1 into Weff[4][256] + beff[4].  Run by one
// 256-thread block (called from the transpose kernel's z==B_ slab).
// ---------------------------------------------------------------------------
__device__ void prep_body(
    const float* __restrict__ W0, const float* __restrict__ b0,
    const float* __restrict__ gamma, const float* __restrict__ beta,
    const float* __restrict__ rmean, const float* __restrict__ rvar,
    const float* __restrict__ W1, const float* __restrict__ b1,
    float* __restrict__ Weff, float* __restrict__ beff)
{
    __shared__ float inv_s[C4_], shift_s[C4_], wg_s[G_][C4_];
    int t = threadIdx.x;
    if (t < C4_) {
        float inv = gamma[t] * rsqrtf(rvar[t] + 1e-5f);
        inv_s[t]   = inv;
        shift_s[t] = (b0[t] - rmean[t]) * inv + beta[t];
    }
    __syncthreads();
    if (t < G_ * C4_) wg_s[t >> 6][t & 63] = W1[t] * inv_s[t & 63];
    __syncthreads();
    float s0 = 0.f, s1 = 0.f, s2 = 0.f, s3 = 0.f;
    for (int o = 0; o < C4_; ++o) {
        float w0 = W0[o * C_ + t];
        s0 += wg_s[0][o] * w0;
        s1 += wg_s[1][o] * w0;
        s2 += wg_s[2][o] * w0;
        s3 += wg_s[3][o] * w0;
    }
    Weff[0*C_ + t] = s0;
    Weff[1*C_ + t] = s1;
    Weff[2*C_ + t] = s2;
    Weff[3*C_ + t] = s3;
    if (t < G_) {
        float s = b1[t];
        for (int o = 0; o < C4_; ++o) s += W1[t*C4_ + o] * shift_s[o];
        beff[t] = s;
    }
}

// ---------------------------------------------------------------------------
// Transpose x (B,C,HW) -> xT (B,HW,C), LDS-free, float4 both sides via 4x4
// register transpose.  Per block: 32 c x 128 hw tile, 256 threads.
// grid.z == B_ slab: block (0,0) additionally runs prep (others no-op).
// ---------------------------------------------------------------------------
__global__ __launch_bounds__(256) void transpose_kernel(
    const float* __restrict__ x, float* __restrict__ xT,
    const float* __restrict__ W0, const float* __restrict__ b0,
    const float* __restrict__ gamma, const float* __restrict__ beta,
    const float* __restrict__ rmean, const float* __restrict__ rvar,
    const float* __restrict__ W1, const float* __restrict__ b1,
    float* __restrict__ Weff, float* __restrict__ beff)
{
    if (blockIdx.z == B_) {
        if (blockIdx.x == 0 && blockIdx.y == 0)
            prep_body(W0, b0, gamma, beta, rmean, rvar, W1, b1, Weff, beff);
        return;
    }
    int t = threadIdx.x;
    int cq  = t & 7;        // 8 c-quads -> 32 channels
    int hw4 = t >> 3;       // 32 hw-quads -> 128 positions
    int hw0 = blockIdx.x * 128, c0 = blockIdx.y * 32, b = blockIdx.z;

    const float* xb = x + (size_t)b * C_ * HW_ + (size_t)(c0 + cq*4) * HW_ + hw0 + hw4*4;
    float4 r0 = *(const float4*)(xb);
    float4 r1 = *(const float4*)(xb +     HW_);
    float4 r2 = *(const float4*)(xb + 2 * HW_);
    float4 r3 = *(const float4*)(xb + 3 * HW_);

    float4 t0 = {r0.x, r1.x, r2.x, r3.x};
    float4 t1 = {r0.y, r1.y, r2.y, r3.y};
    float4 t2 = {r0.z, r1.z, r2.z, r3.z};
    float4 t3 = {r0.w, r1.w, r2.w, r3.w};

    float* xTb = xT + (size_t)b * HW_ * C_ + (size_t)(hw0 + hw4*4) * C_ + c0 + cq*4;
    *(float4*)(xTb)          = t0;
    *(float4*)(xTb +     C_) = t1;
    *(float4*)(xTb + 2 * C_) = t2;
    *(float4*)(xTb + 3 * C_) = t3;
}

// ---------------------------------------------------------------------------
// Main: deformable 3x3 unfold + bilinear + max + 4x256 dot + sigmoid.
// Phase 1: 288 threads compute tap weights + corner byte-offsets for the
//          block's 32 pixels, stash in LDS.
// Phase 2: 8 waves x 4 pixels, processed 2-at-a-time interleaved so 8
//          independent float4 gathers are in flight per tap step (ILP —
//          round-5 profile showed VGPR=32, latency-bound gathers).
// FUSED=1 writes the tiled (B,256,H,W) output directly (full 128B lines).
// ---------------------------------------------------------------------------
template<int FUSED>
__global__ __launch_bounds__(512, 8) void main_kernel(
    const float* __restrict__ xT, const float* __restrict__ offset,
    const float* __restrict__ Weff, const float* __restrict__ beff,
    float* __restrict__ dst)
{
    __shared__ float    wgt_lds[9][PX_][4];
    __shared__ unsigned adr_lds[9][PX_][4];
    __shared__ float    att_lds[G_][PX_];

    int t = threadIdx.x;
    int wave = t >> 6, lane = t & 63;

    // bijective XCD swizzle (NBLK % 8 == 0): 128 consecutive lids per XCD
    int bid = blockIdx.x;
    int lid = (bid & 7) * (NBLK / 8) + (bid >> 3);
    int xc = lid & (NCH_ - 1);
    int y  = (lid >> 2) & (H_ - 1);
    int b  = lid >> 9;
    int x0 = xc * PX_;
    int c0 = lane * 4;

    const float* xTb = xT + (size_t)b * HW_ * C_;

    // ---- phase 1: per-tap parameters, vectorized across threads ----
    if (t < 9 * PX_) {
        int k  = t >> 5, px = t & 31;
        int x  = x0 + px;
        const float* offb = offset + (size_t)b * 18 * HW_ + (size_t)y * W_;
        float oy = offb[(size_t)(2*k    ) * HW_ + x];
        float ox = offb[(size_t)(2*k + 1) * HW_ + x];
        float py = (float)(y + (k/3) - 1) + oy;
        float qx = (float)(x + (k%3) - 1) + ox;
        float y0f = floorf(py), x0f = floorf(qx);
        float fy = py - y0f, fx = qx - x0f;
        float vy0 = (y0f >=  0.f && y0f <= 127.f) ? 1.f : 0.f;
        float vy1 = (y0f >= -1.f && y0f <= 126.f) ? 1.f : 0.f;
        float vx0 = (x0f >=  0.f && x0f <= 127.f) ? 1.f : 0.f;
        float vx1 = (x0f >= -1.f && x0f <= 126.f) ? 1.f : 0.f;
        float wy0 = (1.f - fy) * vy0, wy1 = fy * vy1;
        float wx0 = (1.f - fx) * vx0, wx1 = fx * vx1;
        int iy0 = min(max((int)y0f,     0), H_-1);
        int iy1 = min(max((int)y0f + 1, 0), H_-1);
        int ix0 = min(max((int)x0f,     0), W_-1);
        int ix1 = min(max((int)x0f + 1, 0), W_-1);
        float4 wg = {wy0*wx0, wy0*wx1, wy1*wx0, wy1*wx1};
        uint4  ad = {(unsigned)((iy0*W_ + ix0) << 10),
                     (unsigned)((iy0*W_ + ix1) << 10),
                     (unsigned)((iy1*W_ + ix0) << 10),
                     (unsigned)((iy1*W_ + ix1) << 10)};
        *(float4*)(&wgt_lds[k][px][0]) = wg;
        *(uint4* )(&adr_lds[k][px][0]) = ad;
    }

    // per-lane Weff fragment + beff (independent of phase 1)
    float wf[G_][4];
    #pragma unroll
    for (int g = 0; g < G_; ++g) {
        float4 v = *(const float4*)(Weff + g*C_ + c0);
        wf[g][0] = v.x; wf[g][1] = v.y; wf[g][2] = v.z; wf[g][3] = v.w;
    }
    float be[G_];
    #pragma unroll
    for (int g = 0; g < G_; ++g) be[g] = beff[g];

    __syncthreads();

    // ---- phase 2: gathers + bilinear + max + projection, 2 px interleaved --
    const char* xTc = (const char*)xTb;
    int laneoff = lane << 4;            // c0 * 4 bytes

    #pragma unroll
    for (int i = 0; i < 2; ++i) {
        int pxA = wave * 4 + i * 2;
        int pxB = pxA + 1;
        float fa0 = -3.4028235e38f, fa1 = fa0, fa2 = fa0, fa3 = fa0;
        float fb0 = fa0, fb1 = fa0, fb2 = fa0, fb3 = fa0;

        #pragma unroll
        for (int k = 0; k < 9; ++k) {
            float4 wgA = *(const float4*)(&wgt_lds[k][pxA][0]);
            uint4  adA = *(const uint4* )(&adr_lds[k][pxA][0]);
            float4 wgB = *(const float4*)(&wgt_lds[k][pxB][0]);
            uint4  adB = *(const uint4* )(&adr_lds[k][pxB][0]);
            const float4 a00 = *(const float4*)(xTc + adA.x + laneoff);
            const float4 a01 = *(const float4*)(xTc + adA.y + laneoff);
            const float4 a10 = *(const float4*)(xTc + adA.z + laneoff);
            const float4 a11 = *(const float4*)(xTc + adA.w + laneoff);
            const float4 b00 = *(const float4*)(xTc + adB.x + laneoff);
            const float4 b01 = *(const float4*)(xTc + adB.y + laneoff);
            const float4 b10 = *(const float4*)(xTc + adB.z + laneoff);
            const float4 b11 = *(const float4*)(xTc + adB.w + laneoff);

            float ta0 = wgA.x*a00.x + wgA.y*a01.x + wgA.z*a10.x + wgA.w*a11.x;
            float ta1 = wgA.x*a00.y + wgA.y*a01.y + wgA.z*a10.y + wgA.w*a11.y;
            float ta2 = wgA.x*a00.z + wgA.y*a01.z + wgA.z*a10.z + wgA.w*a11.z;
            float ta3 = wgA.x*a00.w + wgA.y*a01.w + wgA.z*a10.w + wgA.w*a11.w;
            fa0 = fmaxf(fa0, ta0);
            fa1 = fmaxf(fa1, ta1);
            fa2 = fmaxf(fa2, ta2);
            fa3 = fmaxf(fa3, ta3);

            float tb0 = wgB.x*b00.x + wgB.y*b01.x + wgB.z*b10.x + wgB.w*b11.x;
            float tb1 = wgB.x*b00.y + wgB.y*b01.y + wgB.z*b10.y + wgB.w*b11.y;
            float tb2 = wgB.x*b00.z + wgB.y*b01.z + wgB.z*b10.z + wgB.w*b11.z;
            float tb3 = wgB.x*b00.w + wgB.y*b01.w + wgB.z*b10.w + wgB.w*b11.w;
            fb0 = fmaxf(fb0, tb0);
            fb1 = fmaxf(fb1, tb1);
            fb2 = fmaxf(fb2, tb2);
            fb3 = fmaxf(fb3, tb3);
        }

        float pA[G_], pB[G_];
        #pragma unroll
        for (int g = 0; g < G_; ++g) {
            pA[g] = wf[g][0]*fa0 + wf[g][1]*fa1 + wf[g][2]*fa2 + wf[g][3]*fa3;
            pB[g] = wf[g][0]*fb0 + wf[g][1]*fb1 + wf[g][2]*fb2 + wf[g][3]*fb3;
        }

        #pragma unroll
        for (int off2 = 32; off2 > 0; off2 >>= 1) {
            #pragma unroll
            for (int g = 0; g < G_; ++g) {
                pA[g] += __shfl_xor(pA[g], off2);
                pB[g] += __shfl_xor(pB[g], off2);
            }
        }

        if (lane == 0) {
            #pragma unroll
            for (int g = 0; g < G_; ++g) {
                att_lds[g][pxA] = 1.f / (1.f + expf(-(pA[g] + be[g])));
                att_lds[g][pxB] = 1.f / (1.f + expf(-(pB[g] + be[g])));
            }
        }
    }
    __syncthreads();

    if (FUSED) {
        // tiled output: out[b][c][y][x0..x0+31]; 128B (full line) per channel
        float* ob = dst + (size_t)b * C_ * HW_ + (size_t)y * W_ + x0;
        #pragma unroll
        for (int rep = 0; rep < 4; ++rep) {
            int idx = rep * 512 + t;        // float4 slot over 256 ch x 8 quads
            int c   = idx >> 3;
            int x4  = idx & 7;
            f4_t v = *(const f4_t*)(&att_lds[c & 3][x4 * 4]);
            __builtin_nontemporal_store(v, (f4_t*)(ob + (size_t)c * HW_ + x4 * 4));
        }
    } else {
        if (t < G_ * PX_) {
            int g = t >> 5, px = t & 31;
            dst[(size_t)(b*G_ + g) * HW_ + (size_t)y * W_ + x0 + px] = att_lds[g][px];
        }
    }
}

// ---------------------------------------------------------------------------
// Fallback only: tile att (B,4,H,W) -> out (B,256,H,W).
// ---------------------------------------------------------------------------
__global__ __launch_bounds__(256) void expand_kernel(
    const float* __restrict__ att, float* __restrict__ out)
{
    int e4 = blockIdx.x * 256 + threadIdx.x;
    int x4 = e4 & 31;
    int y  = (e4 >> 5) & (H_ - 1);
    int c  = (e4 >> 12) & (C_ - 1);
    int b  = (e4 >> 20) & 1;
    float4 v = *(const float4*)(att + ((size_t)(b*G_ + (c & 3)) * HW_) + y*W_ + x4*4);
    *(float4*)(out + ((size_t)(b*C_ + c) * HW_) + y*W_ + x4*4) = v;
}

// ---------------------------------------------------------------------------
extern "C" void kernel_launch(void* const* d_in, const int* in_sizes, int n_in,
                              void* d_out, int out_size, void* d_ws, size_t ws_size,
                              hipStream_t stream)
{
    (void)in_sizes; (void)n_in; (void)out_size;
    const float* x      = (const float*)d_in[0];
    const float* offset = (const float*)d_in[1];
    const float* W0     = (const float*)d_in[2];
    const float* b0     = (const float*)d_in[3];
    const float* gamma  = (const float*)d_in[4];
    const float* beta   = (const float*)d_in[5];
    const float* rmean  = (const float*)d_in[6];
    const float* rvar   = (const float*)d_in[7];
    const float* W1     = (const float*)d_in[8];
    const float* b1     = (const float*)d_in[9];
    float* out = (float*)d_out;

    const size_t xT_elems = (size_t)B_ * C_ * HW_;
    const size_t need_fused = (xT_elems + G_*C_ + G_ + 64) * sizeof(float);

    if (ws_size >= need_fused) {
        float* xT   = (float*)d_ws;
        float* Weff = xT + xT_elems;
        float* beff = Weff + G_ * C_;
        transpose_kernel<<<dim3(HW_/128, C_/32, B_ + 1), dim3(256), 0, stream>>>(
            x, xT, W0, b0, gamma, beta, rmean, rvar, W1, b1, Weff, beff);
        main_kernel<1><<<dim3(NBLK), dim3(512), 0, stream>>>(
            xT, offset, Weff, beff, out);
    } else {
        float* xT   = out;
        float* att  = (float*)d_ws;
        float* Weff = att + (size_t)B_ * G_ * HW_;
        float* beff = Weff + G_ * C_;
        transpose_kernel<<<dim3(HW_/128, C_/32, B_ + 1), dim3(256), 0, stream>>>(
            x, xT, W0, b0, gamma, beta, rmean, rvar, W1, b1, Weff, beff);
        main_kernel<0><<<dim3(NBLK), dim3(512), 0, stream>>>(
            xT, offset, Weff, beff, att);
        expand_kernel<<<dim3((B_*C_*HW_/4) / 256), dim3(256), 0, stream>>>(att, out);
    }
}

// Round 8
// 167.454 us; speedup vs baseline: 1.0444x; 1.0444x over previous
//
#include <hip/hip_runtime.h>
#include <math.h>

#define B_   2
#define C_   256
#define C4_  64
#define H_   128
#define W_   128
#define HW_  (H_*W_)
#define G_   4
#define PX_  32                       // pixels per main block
#define NCH_ (W_/PX_)                 // 4 chunks per row
#define NBLK (B_*H_*NCH_)             // 1024 blocks

typedef float f4_t __attribute__((ext_vector_type(4)));

// ---------------------------------------------------------------------------
// prep body: fold W0 + BN + W1 into Weff[4][256] + beff[4].  Run by one
// 256-thread block (called from the transpose kernel's z==B_ slab).
// ---------------------------------------------------------------------------
__device__ void prep_body(
    const float* __restrict__ W0, const float* __restrict__ b0,
    const float* __restrict__ gamma, const float* __restrict__ beta,
    const float* __restrict__ rmean, const float* __restrict__ rvar,
    const float* __restrict__ W1, const float* __restrict__ b1,
    float* __restrict__ Weff, float* __restrict__ beff)
{
    __shared__ float inv_s[C4_], shift_s[C4_], wg_s[G_][C4_];
    int t = threadIdx.x;
    if (t < C4_) {
        float inv = gamma[t] * rsqrtf(rvar[t] + 1e-5f);
        inv_s[t]   = inv;
        shift_s[t] = (b0[t] - rmean[t]) * inv + beta[t];
    }
    __syncthreads();
    if (t < G_ * C4_) wg_s[t >> 6][t & 63] = W1[t] * inv_s[t & 63];
    __syncthreads();
    float s0 = 0.f, s1 = 0.f, s2 = 0.f, s3 = 0.f;
    for (int o = 0; o < C4_; ++o) {
        float w0 = W0[o * C_ + t];
        s0 += wg_s[0][o] * w0;
        s1 += wg_s[1][o] * w0;
        s2 += wg_s[2][o] * w0;
        s3 += wg_s[3][o] * w0;
    }
    Weff[0*C_ + t] = s0;
    Weff[1*C_ + t] = s1;
    Weff[2*C_ + t] = s2;
    Weff[3*C_ + t] = s3;
    if (t < G_) {
        float s = b1[t];
        for (int o = 0; o < C4_; ++o) s += W1[t*C4_ + o] * shift_s[o];
        beff[t] = s;
    }
}

// ---------------------------------------------------------------------------
// Transpose x (B,C,HW) -> xT (B,HW,C), LDS-free, float4 both sides via 4x4
// register transpose.  Per block: 32 c x 128 hw tile, 256 threads.
// grid.z == B_ slab: block (0,0) additionally runs prep (others no-op).
// ---------------------------------------------------------------------------
__global__ __launch_bounds__(256) void transpose_kernel(
    const float* __restrict__ x, float* __restrict__ xT,
    const float* __restrict__ W0, const float* __restrict__ b0,
    const float* __restrict__ gamma, const float* __restrict__ beta,
    const float* __restrict__ rmean, const float* __restrict__ rvar,
    const float* __restrict__ W1, const float* __restrict__ b1,
    float* __restrict__ Weff, float* __restrict__ beff)
{
    if (blockIdx.z == B_) {
        if (blockIdx.x == 0 && blockIdx.y == 0)
            prep_body(W0, b0, gamma, beta, rmean, rvar, W1, b1, Weff, beff);
        return;
    }
    int t = threadIdx.x;
    int cq  = t & 7;        // 8 c-quads -> 32 channels
    int hw4 = t >> 3;       // 32 hw-quads -> 128 positions
    int hw0 = blockIdx.x * 128, c0 = blockIdx.y * 32, b = blockIdx.z;

    const float* xb = x + (size_t)b * C_ * HW_ + (size_t)(c0 + cq*4) * HW_ + hw0 + hw4*4;
    float4 r0 = *(const float4*)(xb);
    float4 r1 = *(const float4*)(xb +     HW_);
    float4 r2 = *(const float4*)(xb + 2 * HW_);
    float4 r3 = *(const float4*)(xb + 3 * HW_);

    float4 t0 = {r0.x, r1.x, r2.x, r3.x};
    float4 t1 = {r0.y, r1.y, r2.y, r3.y};
    float4 t2 = {r0.z, r1.z, r2.z, r3.z};
    float4 t3 = {r0.w, r1.w, r2.w, r3.w};

    float* xTb = xT + (size_t)b * HW_ * C_ + (size_t)(hw0 + hw4*4) * C_ + c0 + cq*4;
    *(float4*)(xTb)          = t0;
    *(float4*)(xTb +     C_) = t1;
    *(float4*)(xTb + 2 * C_) = t2;
    *(float4*)(xTb + 3 * C_) = t3;
}

// ---------------------------------------------------------------------------
// Main: deformable 3x3 unfold + bilinear + max + 4x256 dot + sigmoid.
// Phase 1: 288 threads compute tap weights + corner byte-offsets for the
//          block's 32 pixels, stash in LDS.
// Phase 2: 8 waves x 4 pixels, ALL FOUR pixels interleaved per tap step ->
//          16 independent float4 gathers in flight (launch_bounds (512,4)
//          gives the 128-VGPR budget this needs; (512,8) spilled in R6).
//          Weff/beff fragments loaded AFTER the tap loop (L2-hot) to keep
//          loop-carried register pressure down.
// FUSED=1 writes the tiled (B,256,H,W) output directly (full 128B lines).
// ---------------------------------------------------------------------------
template<int FUSED>
__global__ __launch_bounds__(512, 4) void main_kernel(
    const float* __restrict__ xT, const float* __restrict__ offset,
    const float* __restrict__ Weff, const float* __restrict__ beff,
    float* __restrict__ dst)
{
    __shared__ float    wgt_lds[9][PX_][4];
    __shared__ unsigned adr_lds[9][PX_][4];
    __shared__ float    att_lds[G_][PX_];

    int t = threadIdx.x;
    int wave = t >> 6, lane = t & 63;

    // bijective XCD swizzle (NBLK % 8 == 0): 128 consecutive lids per XCD
    int bid = blockIdx.x;
    int lid = (bid & 7) * (NBLK / 8) + (bid >> 3);
    int xc = lid & (NCH_ - 1);
    int y  = (lid >> 2) & (H_ - 1);
    int b  = lid >> 9;
    int x0 = xc * PX_;
    int c0 = lane * 4;

    const float* xTb = xT + (size_t)b * HW_ * C_;

    // ---- phase 1: per-tap parameters, vectorized across threads ----
    if (t < 9 * PX_) {
        int k  = t >> 5, px = t & 31;
        int x  = x0 + px;
        const float* offb = offset + (size_t)b * 18 * HW_ + (size_t)y * W_;
        float oy = offb[(size_t)(2*k    ) * HW_ + x];
        float ox = offb[(size_t)(2*k + 1) * HW_ + x];
        float py = (float)(y + (k/3) - 1) + oy;
        float qx = (float)(x + (k%3) - 1) + ox;
        float y0f = floorf(py), x0f = floorf(qx);
        float fy = py - y0f, fx = qx - x0f;
        float vy0 = (y0f >=  0.f && y0f <= 127.f) ? 1.f : 0.f;
        float vy1 = (y0f >= -1.f && y0f <= 126.f) ? 1.f : 0.f;
        float vx0 = (x0f >=  0.f && x0f <= 127.f) ? 1.f : 0.f;
        float vx1 = (x0f >= -1.f && x0f <= 126.f) ? 1.f : 0.f;
        float wy0 = (1.f - fy) * vy0, wy1 = fy * vy1;
        float wx0 = (1.f - fx) * vx0, wx1 = fx * vx1;
        int iy0 = min(max((int)y0f,     0), H_-1);
        int iy1 = min(max((int)y0f + 1, 0), H_-1);
        int ix0 = min(max((int)x0f,     0), W_-1);
        int ix1 = min(max((int)x0f + 1, 0), W_-1);
        float4 wg = {wy0*wx0, wy0*wx1, wy1*wx0, wy1*wx1};
        uint4  ad = {(unsigned)((iy0*W_ + ix0) << 10),
                     (unsigned)((iy0*W_ + ix1) << 10),
                     (unsigned)((iy1*W_ + ix0) << 10),
                     (unsigned)((iy1*W_ + ix1) << 10)};
        *(float4*)(&wgt_lds[k][px][0]) = wg;
        *(uint4* )(&adr_lds[k][px][0]) = ad;
    }

    __syncthreads();

    // ---- phase 2: gathers + bilinear + max, 4 px fully interleaved ----
    const char* xTc = (const char*)xTb;
    int laneoff = lane << 4;            // c0 * 4 bytes
    int pxb = wave * 4;

    float f0c0 = -3.4028235e38f, f0c1 = f0c0, f0c2 = f0c0, f0c3 = f0c0;
    float f1c0 = f0c0, f1c1 = f0c0, f1c2 = f0c0, f1c3 = f0c0;
    float f2c0 = f0c0, f2c1 = f0c0, f2c2 = f0c0, f2c3 = f0c0;
    float f3c0 = f0c0, f3c1 = f0c0, f3c2 = f0c0, f3c3 = f0c0;

    #pragma unroll
    for (int k = 0; k < 9; ++k) {
        uint4  ad0 = *(const uint4* )(&adr_lds[k][pxb + 0][0]);
        uint4  ad1 = *(const uint4* )(&adr_lds[k][pxb + 1][0]);
        uint4  ad2 = *(const uint4* )(&adr_lds[k][pxb + 2][0]);
        uint4  ad3 = *(const uint4* )(&adr_lds[k][pxb + 3][0]);

        const float4 a00 = *(const float4*)(xTc + ad0.x + laneoff);
        const float4 a01 = *(const float4*)(xTc + ad0.y + laneoff);
        const float4 a10 = *(const float4*)(xTc + ad0.z + laneoff);
        const float4 a11 = *(const float4*)(xTc + ad0.w + laneoff);
        const float4 b00 = *(const float4*)(xTc + ad1.x + laneoff);
        const float4 b01 = *(const float4*)(xTc + ad1.y + laneoff);
        const float4 b10 = *(const float4*)(xTc + ad1.z + laneoff);
        const float4 b11 = *(const float4*)(xTc + ad1.w + laneoff);
        const float4 c00 = *(const float4*)(xTc + ad2.x + laneoff);
        const float4 c01 = *(const float4*)(xTc + ad2.y + laneoff);
        const float4 c10 = *(const float4*)(xTc + ad2.z + laneoff);
        const float4 c11 = *(const float4*)(xTc + ad2.w + laneoff);
        const float4 d00 = *(const float4*)(xTc + ad3.x + laneoff);
        const float4 d01 = *(const float4*)(xTc + ad3.y + laneoff);
        const float4 d10 = *(const float4*)(xTc + ad3.z + laneoff);
        const float4 d11 = *(const float4*)(xTc + ad3.w + laneoff);

        float4 wg0 = *(const float4*)(&wgt_lds[k][pxb + 0][0]);
        float4 wg1 = *(const float4*)(&wgt_lds[k][pxb + 1][0]);
        float4 wg2 = *(const float4*)(&wgt_lds[k][pxb + 2][0]);
        float4 wg3 = *(const float4*)(&wgt_lds[k][pxb + 3][0]);

        f0c0 = fmaxf(f0c0, wg0.x*a00.x + wg0.y*a01.x + wg0.z*a10.x + wg0.w*a11.x);
        f0c1 = fmaxf(f0c1, wg0.x*a00.y + wg0.y*a01.y + wg0.z*a10.y + wg0.w*a11.y);
        f0c2 = fmaxf(f0c2, wg0.x*a00.z + wg0.y*a01.z + wg0.z*a10.z + wg0.w*a11.z);
        f0c3 = fmaxf(f0c3, wg0.x*a00.w + wg0.y*a01.w + wg0.z*a10.w + wg0.w*a11.w);

        f1c0 = fmaxf(f1c0, wg1.x*b00.x + wg1.y*b01.x + wg1.z*b10.x + wg1.w*b11.x);
        f1c1 = fmaxf(f1c1, wg1.x*b00.y + wg1.y*b01.y + wg1.z*b10.y + wg1.w*b11.y);
        f1c2 = fmaxf(f1c2, wg1.x*b00.z + wg1.y*b01.z + wg1.z*b10.z + wg1.w*b11.z);
        f1c3 = fmaxf(f1c3, wg1.x*b00.w + wg1.y*b01.w + wg1.z*b10.w + wg1.w*b11.w);

        f2c0 = fmaxf(f2c0, wg2.x*c00.x + wg2.y*c01.x + wg2.z*c10.x + wg2.w*c11.x);
        f2c1 = fmaxf(f2c1, wg2.x*c00.y + wg2.y*c01.y + wg2.z*c10.y + wg2.w*c11.y);
        f2c2 = fmaxf(f2c2, wg2.x*c00.z + wg2.y*c01.z + wg2.z*c10.z + wg2.w*c11.z);
        f2c3 = fmaxf(f2c3, wg2.x*c00.w + wg2.y*c01.w + wg2.z*c10.w + wg2.w*c11.w);

        f3c0 = fmaxf(f3c0, wg3.x*d00.x + wg3.y*d01.x + wg3.z*d10.x + wg3.w*d11.x);
        f3c1 = fmaxf(f3c1, wg3.x*d00.y + wg3.y*d01.y + wg3.z*d10.y + wg3.w*d11.y);
        f3c2 = fmaxf(f3c2, wg3.x*d00.z + wg3.y*d01.z + wg3.z*d10.z + wg3.w*d11.z);
        f3c3 = fmaxf(f3c3, wg3.x*d00.w + wg3.y*d01.w + wg3.z*d10.w + wg3.w*d11.w);
    }

    // ---- projection: load Weff fragment now (L2-hot, once per wave) ----
    float4 w0v = *(const float4*)(Weff + 0*C_ + c0);
    float4 w1v = *(const float4*)(Weff + 1*C_ + c0);
    float4 w2v = *(const float4*)(Weff + 2*C_ + c0);
    float4 w3v = *(const float4*)(Weff + 3*C_ + c0);
    float be0 = beff[0], be1 = beff[1], be2 = beff[2], be3 = beff[3];

    float p0[G_], p1[G_], p2[G_], p3[G_];
    p0[0] = w0v.x*f0c0 + w0v.y*f0c1 + w0v.z*f0c2 + w0v.w*f0c3;
    p0[1] = w1v.x*f0c0 + w1v.y*f0c1 + w1v.z*f0c2 + w1v.w*f0c3;
    p0[2] = w2v.x*f0c0 + w2v.y*f0c1 + w2v.z*f0c2 + w2v.w*f0c3;
    p0[3] = w3v.x*f0c0 + w3v.y*f0c1 + w3v.z*f0c2 + w3v.w*f0c3;
    p1[0] = w0v.x*f1c0 + w0v.y*f1c1 + w0v.z*f1c2 + w0v.w*f1c3;
    p1[1] = w1v.x*f1c0 + w1v.y*f1c1 + w1v.z*f1c2 + w1v.w*f1c3;
    p1[2] = w2v.x*f1c0 + w2v.y*f1c1 + w2v.z*f1c2 + w2v.w*f1c3;
    p1[3] = w3v.x*f1c0 + w3v.y*f1c1 + w3v.z*f1c2 + w3v.w*f1c3;
    p2[0] = w0v.x*f2c0 + w0v.y*f2c1 + w0v.z*f2c2 + w0v.w*f2c3;
    p2[1] = w1v.x*f2c0 + w1v.y*f2c1 + w1v.z*f2c2 + w1v.w*f2c3;
    p2[2] = w2v.x*f2c0 + w2v.y*f2c1 + w2v.z*f2c2 + w2v.w*f2c3;
    p2[3] = w3v.x*f2c0 + w3v.y*f2c1 + w3v.z*f2c2 + w3v.w*f2c3;
    p3[0] = w0v.x*f3c0 + w0v.y*f3c1 + w0v.z*f3c2 + w0v.w*f3c3;
    p3[1] = w1v.x*f3c0 + w1v.y*f3c1 + w1v.z*f3c2 + w1v.w*f3c3;
    p3[2] = w2v.x*f3c0 + w2v.y*f3c1 + w2v.z*f3c2 + w2v.w*f3c3;
    p3[3] = w3v.x*f3c0 + w3v.y*f3c1 + w3v.z*f3c2 + w3v.w*f3c3;

    #pragma unroll
    for (int off2 = 32; off2 > 0; off2 >>= 1) {
        #pragma unroll
        for (int g = 0; g < G_; ++g) {
            p0[g] += __shfl_xor(p0[g], off2);
            p1[g] += __shfl_xor(p1[g], off2);
            p2[g] += __shfl_xor(p2[g], off2);
            p3[g] += __shfl_xor(p3[g], off2);
        }
    }

    if (lane == 0) {
        float bev[G_] = {be0, be1, be2, be3};
        #pragma unroll
        for (int g = 0; g < G_; ++g) {
            att_lds[g][pxb + 0] = 1.f / (1.f + expf(-(p0[g] + bev[g])));
            att_lds[g][pxb + 1] = 1.f / (1.f + expf(-(p1[g] + bev[g])));
            att_lds[g][pxb + 2] = 1.f / (1.f + expf(-(p2[g] + bev[g])));
            att_lds[g][pxb + 3] = 1.f / (1.f + expf(-(p3[g] + bev[g])));
        }
    }
    __syncthreads();

    if (FUSED) {
        // tiled output: out[b][c][y][x0..x0+31]; 128B (full line) per channel
        float* ob = dst + (size_t)b * C_ * HW_ + (size_t)y * W_ + x0;
        #pragma unroll
        for (int rep = 0; rep < 4; ++rep) {
            int idx = rep * 512 + t;        // float4 slot over 256 ch x 8 quads
            int c   = idx >> 3;
            int x4  = idx & 7;
            f4_t v = *(const f4_t*)(&att_lds[c & 3][x4 * 4]);
            __builtin_nontemporal_store(v, (f4_t*)(ob + (size_t)c * HW_ + x4 * 4));
        }
    } else {
        if (t < G_ * PX_) {
            int g = t >> 5, px = t & 31;
            dst[(size_t)(b*G_ + g) * HW_ + (size_t)y * W_ + x0 + px] = att_lds[g][px];
        }
    }
}

// ---------------------------------------------------------------------------
// Fallback only: tile att (B,4,H,W) -> out (B,256,H,W).
// ---------------------------------------------------------------------------
__global__ __launch_bounds__(256) void expand_kernel(
    const float* __restrict__ att, float* __restrict__ out)
{
    int e4 = blockIdx.x * 256 + threadIdx.x;
    int x4 = e4 & 31;
    int y  = (e4 >> 5) & (H_ - 1);
    int c  = (e4 >> 12) & (C_ - 1);
    int b  = (e4 >> 20) & 1;
    float4 v = *(const float4*)(att + ((size_t)(b*G_ + (c & 3)) * HW_) + y*W_ + x4*4);
    *(float4*)(out + ((size_t)(b*C_ + c) * HW_) + y*W_ + x4*4) = v;
}

// ---------------------------------------------------------------------------
extern "C" void kernel_launch(void* const* d_in, const int* in_sizes, int n_in,
                              void* d_out, int out_size, void* d_ws, size_t ws_size,
                              hipStream_t stream)
{
    (void)in_sizes; (void)n_in; (void)out_size;
    const float* x      = (const float*)d_in[0];
    const float* offset = (const float*)d_in[1];
    const float* W0     = (const float*)d_in[2];
    const float* b0     = (const float*)d_in[3];
    const float* gamma  = (const float*)d_in[4];
    const float* beta   = (const float*)d_in[5];
    const float* rmean  = (const float*)d_in[6];
    const float* rvar   = (const float*)d_in[7];
    const float* W1     = (const float*)d_in[8];
    const float* b1     = (const float*)d_in[9];
    float* out = (float*)d_out;

    const size_t xT_elems = (size_t)B_ * C_ * HW_;
    const size_t need_fused = (xT_elems + G_*C_ + G_ + 64) * sizeof(float);

    if (ws_size >= need_fused) {
        float* xT   = (float*)d_ws;
        float* Weff = xT + xT_elems;
        float* beff = Weff + G_ * C_;
        transpose_kernel<<<dim3(HW_/128, C_/32, B_ + 1), dim3(256), 0, stream>>>(
            x, xT, W0, b0, gamma, beta, rmean, rvar, W1, b1, Weff, beff);
        main_kernel<1><<<dim3(NBLK), dim3(512), 0, stream>>>(
            xT, offset, Weff, beff, out);
    } else {
        float* xT   = out;
        float* att  = (float*)d_ws;
        float* Weff = att + (size_t)B_ * G_ * HW_;
        float* beff = Weff + G_ * C_;
        transpose_kernel<<<dim3(HW_/128, C_/32, B_ + 1), dim3(256), 0, stream>>>(
            x, xT, W0, b0, gamma, beta, rmean, rvar, W1, b1, Weff, beff);
        main_kernel<0><<<dim3(NBLK), dim3(512), 0, stream>>>(
            xT, offset, Weff, beff, att);
        expand_kernel<<<dim3((B_*C_*HW_/4) / 256), dim3(256), 0, stream>>>(att, out);
    }
}

// Round 9
// 158.671 us; speedup vs baseline: 1.1022x; 1.0553x over previous
//
#include <hip/hip_runtime.h>
#include <math.h>

#define B_   2
#define C_   256
#define C4_  64
#define H_   128
#define W_   128
#define HW_  (H_*W_)
#define G_   4
#define PX_  32                       // pixels per main block
#define NCH_ (W_/PX_)                 // 4 chunks per row
#define NBLK (B_*H_*NCH_)             // 1024 blocks

typedef float f4_t __attribute__((ext_vector_type(4)));

// ---------------------------------------------------------------------------
// prep body: fold W0 + BN + W1 into Weff[4][256] + beff[4].  Run by one
// 256-thread block (called from the transpose kernel's z==B_ slab).
// ---------------------------------------------------------------------------
__device__ void prep_body(
    const float* __restrict__ W0, const float* __restrict__ b0,
    const float* __restrict__ gamma, const float* __restrict__ beta,
    const float* __restrict__ rmean, const float* __restrict__ rvar,
    const float* __restrict__ W1, const float* __restrict__ b1,
    float* __restrict__ Weff, float* __restrict__ beff)
{
    __shared__ float inv_s[C4_], shift_s[C4_], wg_s[G_][C4_];
    int t = threadIdx.x;
    if (t < C4_) {
        float inv = gamma[t] * rsqrtf(rvar[t] + 1e-5f);
        inv_s[t]   = inv;
        shift_s[t] = (b0[t] - rmean[t]) * inv + beta[t];
    }
    __syncthreads();
    if (t < G_ * C4_) wg_s[t >> 6][t & 63] = W1[t] * inv_s[t & 63];
    __syncthreads();
    float s0 = 0.f, s1 = 0.f, s2 = 0.f, s3 = 0.f;
    for (int o = 0; o < C4_; ++o) {
        float w0 = W0[o * C_ + t];
        s0 += wg_s[0][o] * w0;
        s1 += wg_s[1][o] * w0;
        s2 += wg_s[2][o] * w0;
        s3 += wg_s[3][o] * w0;
    }
    Weff[0*C_ + t] = s0;
    Weff[1*C_ + t] = s1;
    Weff[2*C_ + t] = s2;
    Weff[3*C_ + t] = s3;
    if (t < G_) {
        float s = b1[t];
        for (int o = 0; o < C4_; ++o) s += W1[t*C4_ + o] * shift_s[o];
        beff[t] = s;
    }
}

// ---------------------------------------------------------------------------
// Transpose x (B,C,HW) -> xT (B,HW,C), LDS-free, float4 both sides via 4x4
// register transpose.  Per block: 32 c x 128 hw tile, 256 threads.
// grid.z == B_ slab: block (0,0) additionally runs prep (others no-op).
// ---------------------------------------------------------------------------
__global__ __launch_bounds__(256) void transpose_kernel(
    const float* __restrict__ x, float* __restrict__ xT,
    const float* __restrict__ W0, const float* __restrict__ b0,
    const float* __restrict__ gamma, const float* __restrict__ beta,
    const float* __restrict__ rmean, const float* __restrict__ rvar,
    const float* __restrict__ W1, const float* __restrict__ b1,
    float* __restrict__ Weff, float* __restrict__ beff)
{
    if (blockIdx.z == B_) {
        if (blockIdx.x == 0 && blockIdx.y == 0)
            prep_body(W0, b0, gamma, beta, rmean, rvar, W1, b1, Weff, beff);
        return;
    }
    int t = threadIdx.x;
    int cq  = t & 7;        // 8 c-quads -> 32 channels
    int hw4 = t >> 3;       // 32 hw-quads -> 128 positions
    int hw0 = blockIdx.x * 128, c0 = blockIdx.y * 32, b = blockIdx.z;

    const float* xb = x + (size_t)b * C_ * HW_ + (size_t)(c0 + cq*4) * HW_ + hw0 + hw4*4;
    float4 r0 = *(const float4*)(xb);
    float4 r1 = *(const float4*)(xb +     HW_);
    float4 r2 = *(const float4*)(xb + 2 * HW_);
    float4 r3 = *(const float4*)(xb + 3 * HW_);

    float4 t0 = {r0.x, r1.x, r2.x, r3.x};
    float4 t1 = {r0.y, r1.y, r2.y, r3.y};
    float4 t2 = {r0.z, r1.z, r2.z, r3.z};
    float4 t3 = {r0.w, r1.w, r2.w, r3.w};

    float* xTb = xT + (size_t)b * HW_ * C_ + (size_t)(hw0 + hw4*4) * C_ + c0 + cq*4;
    *(float4*)(xTb)          = t0;
    *(float4*)(xTb +     C_) = t1;
    *(float4*)(xTb + 2 * C_) = t2;
    *(float4*)(xTb + 3 * C_) = t3;
}

// ---------------------------------------------------------------------------
// Main: deformable 3x3 unfold + bilinear + max + 4x256 dot + sigmoid.
// Phase 1: 288 threads compute tap weights + corner byte-offsets for the
//          block's 32 pixels, stash in LDS.
// Phase 2: 8 waves x 4 pixels, ALL FOUR pixels interleaved per tap step ->
//          16 independent float4 gathers in flight.
// __launch_bounds__(512, 2): empirically hipcc treats arg2 as CUDA
// min-BLOCKS-per-CU: (512,8)->32 VGPR cap (R5/R6), (512,4)->64 (R8, spilled
// 40MB).  2 blocks/CU -> 4 waves/EU -> 128-VGPR cap, fits the ~110-reg loop.
// FUSED=1 writes the tiled (B,256,H,W) output directly (full 128B lines).
// ---------------------------------------------------------------------------
template<int FUSED>
__global__ __launch_bounds__(512, 2) void main_kernel(
    const float* __restrict__ xT, const float* __restrict__ offset,
    const float* __restrict__ Weff, const float* __restrict__ beff,
    float* __restrict__ dst)
{
    __shared__ float    wgt_lds[9][PX_][4];
    __shared__ unsigned adr_lds[9][PX_][4];
    __shared__ float    att_lds[G_][PX_];

    int t = threadIdx.x;
    int wave = t >> 6, lane = t & 63;

    // bijective XCD swizzle (NBLK % 8 == 0): 128 consecutive lids per XCD
    int bid = blockIdx.x;
    int lid = (bid & 7) * (NBLK / 8) + (bid >> 3);
    int xc = lid & (NCH_ - 1);
    int y  = (lid >> 2) & (H_ - 1);
    int b  = lid >> 9;
    int x0 = xc * PX_;
    int c0 = lane * 4;

    const float* xTb = xT + (size_t)b * HW_ * C_;

    // ---- phase 1: per-tap parameters, vectorized across threads ----
    if (t < 9 * PX_) {
        int k  = t >> 5, px = t & 31;
        int x  = x0 + px;
        const float* offb = offset + (size_t)b * 18 * HW_ + (size_t)y * W_;
        float oy = offb[(size_t)(2*k    ) * HW_ + x];
        float ox = offb[(size_t)(2*k + 1) * HW_ + x];
        float py = (float)(y + (k/3) - 1) + oy;
        float qx = (float)(x + (k%3) - 1) + ox;
        float y0f = floorf(py), x0f = floorf(qx);
        float fy = py - y0f, fx = qx - x0f;
        float vy0 = (y0f >=  0.f && y0f <= 127.f) ? 1.f : 0.f;
        float vy1 = (y0f >= -1.f && y0f <= 126.f) ? 1.f : 0.f;
        float vx0 = (x0f >=  0.f && x0f <= 127.f) ? 1.f : 0.f;
        float vx1 = (x0f >= -1.f && x0f <= 126.f) ? 1.f : 0.f;
        float wy0 = (1.f - fy) * vy0, wy1 = fy * vy1;
        float wx0 = (1.f - fx) * vx0, wx1 = fx * vx1;
        int iy0 = min(max((int)y0f,     0), H_-1);
        int iy1 = min(max((int)y0f + 1, 0), H_-1);
        int ix0 = min(max((int)x0f,     0), W_-1);
        int ix1 = min(max((int)x0f + 1, 0), W_-1);
        float4 wg = {wy0*wx0, wy0*wx1, wy1*wx0, wy1*wx1};
        uint4  ad = {(unsigned)((iy0*W_ + ix0) << 10),
                     (unsigned)((iy0*W_ + ix1) << 10),
                     (unsigned)((iy1*W_ + ix0) << 10),
                     (unsigned)((iy1*W_ + ix1) << 10)};
        *(float4*)(&wgt_lds[k][px][0]) = wg;
        *(uint4* )(&adr_lds[k][px][0]) = ad;
    }

    __syncthreads();

    // ---- phase 2: gathers + bilinear + max, 4 px fully interleaved ----
    const char* xTc = (const char*)xTb;
    int laneoff = lane << 4;            // c0 * 4 bytes
    int pxb = wave * 4;

    float f0c0 = -3.4028235e38f, f0c1 = f0c0, f0c2 = f0c0, f0c3 = f0c0;
    float f1c0 = f0c0, f1c1 = f0c0, f1c2 = f0c0, f1c3 = f0c0;
    float f2c0 = f0c0, f2c1 = f0c0, f2c2 = f0c0, f2c3 = f0c0;
    float f3c0 = f0c0, f3c1 = f0c0, f3c2 = f0c0, f3c3 = f0c0;

    #pragma unroll
    for (int k = 0; k < 9; ++k) {
        uint4  ad0 = *(const uint4* )(&adr_lds[k][pxb + 0][0]);
        uint4  ad1 = *(const uint4* )(&adr_lds[k][pxb + 1][0]);
        uint4  ad2 = *(const uint4* )(&adr_lds[k][pxb + 2][0]);
        uint4  ad3 = *(const uint4* )(&adr_lds[k][pxb + 3][0]);

        const float4 a00 = *(const float4*)(xTc + ad0.x + laneoff);
        const float4 a01 = *(const float4*)(xTc + ad0.y + laneoff);
        const float4 a10 = *(const float4*)(xTc + ad0.z + laneoff);
        const float4 a11 = *(const float4*)(xTc + ad0.w + laneoff);
        const float4 b00 = *(const float4*)(xTc + ad1.x + laneoff);
        const float4 b01 = *(const float4*)(xTc + ad1.y + laneoff);
        const float4 b10 = *(const float4*)(xTc + ad1.z + laneoff);
        const float4 b11 = *(const float4*)(xTc + ad1.w + laneoff);
        const float4 c00 = *(const float4*)(xTc + ad2.x + laneoff);
        const float4 c01 = *(const float4*)(xTc + ad2.y + laneoff);
        const float4 c10 = *(const float4*)(xTc + ad2.z + laneoff);
        const float4 c11 = *(const float4*)(xTc + ad2.w + laneoff);
        const float4 d00 = *(const float4*)(xTc + ad3.x + laneoff);
        const float4 d01 = *(const float4*)(xTc + ad3.y + laneoff);
        const float4 d10 = *(const float4*)(xTc + ad3.z + laneoff);
        const float4 d11 = *(const float4*)(xTc + ad3.w + laneoff);

        float4 wg0 = *(const float4*)(&wgt_lds[k][pxb + 0][0]);
        float4 wg1 = *(const float4*)(&wgt_lds[k][pxb + 1][0]);
        float4 wg2 = *(const float4*)(&wgt_lds[k][pxb + 2][0]);
        float4 wg3 = *(const float4*)(&wgt_lds[k][pxb + 3][0]);

        f0c0 = fmaxf(f0c0, wg0.x*a00.x + wg0.y*a01.x + wg0.z*a10.x + wg0.w*a11.x);
        f0c1 = fmaxf(f0c1, wg0.x*a00.y + wg0.y*a01.y + wg0.z*a10.y + wg0.w*a11.y);
        f0c2 = fmaxf(f0c2, wg0.x*a00.z + wg0.y*a01.z + wg0.z*a10.z + wg0.w*a11.z);
        f0c3 = fmaxf(f0c3, wg0.x*a00.w + wg0.y*a01.w + wg0.z*a10.w + wg0.w*a11.w);

        f1c0 = fmaxf(f1c0, wg1.x*b00.x + wg1.y*b01.x + wg1.z*b10.x + wg1.w*b11.x);
        f1c1 = fmaxf(f1c1, wg1.x*b00.y + wg1.y*b01.y + wg1.z*b10.y + wg1.w*b11.y);
        f1c2 = fmaxf(f1c2, wg1.x*b00.z + wg1.y*b01.z + wg1.z*b10.z + wg1.w*b11.z);
        f1c3 = fmaxf(f1c3, wg1.x*b00.w + wg1.y*b01.w + wg1.z*b10.w + wg1.w*b11.w);

        f2c0 = fmaxf(f2c0, wg2.x*c00.x + wg2.y*c01.x + wg2.z*c10.x + wg2.w*c11.x);
        f2c1 = fmaxf(f2c1, wg2.x*c00.y + wg2.y*c01.y + wg2.z*c10.y + wg2.w*c11.y);
        f2c2 = fmaxf(f2c2, wg2.x*c00.z + wg2.y*c01.z + wg2.z*c10.z + wg2.w*c11.z);
        f2c3 = fmaxf(f2c3, wg2.x*c00.w + wg2.y*c01.w + wg2.z*c10.w + wg2.w*c11.w);

        f3c0 = fmaxf(f3c0, wg3.x*d00.x + wg3.y*d01.x + wg3.z*d10.x + wg3.w*d11.x);
        f3c1 = fmaxf(f3c1, wg3.x*d00.y + wg3.y*d01.y + wg3.z*d10.y + wg3.w*d11.y);
        f3c2 = fmaxf(f3c2, wg3.x*d00.z + wg3.y*d01.z + wg3.z*d10.z + wg3.w*d11.z);
        f3c3 = fmaxf(f3c3, wg3.x*d00.w + wg3.y*d01.w + wg3.z*d10.w + wg3.w*d11.w);
    }

    // ---- projection: load Weff fragment now (L2-hot, once per wave) ----
    float4 w0v = *(const float4*)(Weff + 0*C_ + c0);
    float4 w1v = *(const float4*)(Weff + 1*C_ + c0);
    float4 w2v = *(const float4*)(Weff + 2*C_ + c0);
    float4 w3v = *(const float4*)(Weff + 3*C_ + c0);
    float be0 = beff[0], be1 = beff[1], be2 = beff[2], be3 = beff[3];

    float p0[G_], p1[G_], p2[G_], p3[G_];
    p0[0] = w0v.x*f0c0 + w0v.y*f0c1 + w0v.z*f0c2 + w0v.w*f0c3;
    p0[1] = w1v.x*f0c0 + w1v.y*f0c1 + w1v.z*f0c2 + w1v.w*f0c3;
    p0[2] = w2v.x*f0c0 + w2v.y*f0c1 + w2v.z*f0c2 + w2v.w*f0c3;
    p0[3] = w3v.x*f0c0 + w3v.y*f0c1 + w3v.z*f0c2 + w3v.w*f0c3;
    p1[0] = w0v.x*f1c0 + w0v.y*f1c1 + w0v.z*f1c2 + w0v.w*f1c3;
    p1[1] = w1v.x*f1c0 + w1v.y*f1c1 + w1v.z*f1c2 + w1v.w*f1c3;
    p1[2] = w2v.x*f1c0 + w2v.y*f1c1 + w2v.z*f1c2 + w2v.w*f1c3;
    p1[3] = w3v.x*f1c0 + w3v.y*f1c1 + w3v.z*f1c2 + w3v.w*f1c3;
    p2[0] = w0v.x*f2c0 + w0v.y*f2c1 + w0v.z*f2c2 + w0v.w*f2c3;
    p2[1] = w1v.x*f2c0 + w1v.y*f2c1 + w1v.z*f2c2 + w1v.w*f2c3;
    p2[2] = w2v.x*f2c0 + w2v.y*f2c1 + w2v.z*f2c2 + w2v.w*f2c3;
    p2[3] = w3v.x*f2c0 + w3v.y*f2c1 + w3v.z*f2c2 + w3v.w*f2c3;
    p3[0] = w0v.x*f3c0 + w0v.y*f3c1 + w0v.z*f3c2 + w0v.w*f3c3;
    p3[1] = w1v.x*f3c0 + w1v.y*f3c1 + w1v.z*f3c2 + w1v.w*f3c3;
    p3[2] = w2v.x*f3c0 + w2v.y*f3c1 + w2v.z*f3c2 + w2v.w*f3c3;
    p3[3] = w3v.x*f3c0 + w3v.y*f3c1 + w3v.z*f3c2 + w3v.w*f3c3;

    #pragma unroll
    for (int off2 = 32; off2 > 0; off2 >>= 1) {
        #pragma unroll
        for (int g = 0; g < G_; ++g) {
            p0[g] += __shfl_xor(p0[g], off2);
            p1[g] += __shfl_xor(p1[g], off2);
            p2[g] += __shfl_xor(p2[g], off2);
            p3[g] += __shfl_xor(p3[g], off2);
        }
    }

    if (lane == 0) {
        float bev[G_] = {be0, be1, be2, be3};
        #pragma unroll
        for (int g = 0; g < G_; ++g) {
            att_lds[g][pxb + 0] = 1.f / (1.f + expf(-(p0[g] + bev[g])));
            att_lds[g][pxb + 1] = 1.f / (1.f + expf(-(p1[g] + bev[g])));
            att_lds[g][pxb + 2] = 1.f / (1.f + expf(-(p2[g] + bev[g])));
            att_lds[g][pxb + 3] = 1.f / (1.f + expf(-(p3[g] + bev[g])));
        }
    }
    __syncthreads();

    if (FUSED) {
        // tiled output: out[b][c][y][x0..x0+31]; 128B (full line) per channel
        float* ob = dst + (size_t)b * C_ * HW_ + (size_t)y * W_ + x0;
        #pragma unroll
        for (int rep = 0; rep < 4; ++rep) {
            int idx = rep * 512 + t;        // float4 slot over 256 ch x 8 quads
            int c   = idx >> 3;
            int x4  = idx & 7;
            f4_t v = *(const f4_t*)(&att_lds[c & 3][x4 * 4]);
            __builtin_nontemporal_store(v, (f4_t*)(ob + (size_t)c * HW_ + x4 * 4));
        }
    } else {
        if (t < G_ * PX_) {
            int g = t >> 5, px = t & 31;
            dst[(size_t)(b*G_ + g) * HW_ + (size_t)y * W_ + x0 + px] = att_lds[g][px];
        }
    }
}

// ---------------------------------------------------------------------------
// Fallback only: tile att (B,4,H,W) -> out (B,256,H,W).
// ---------------------------------------------------------------------------
__global__ __launch_bounds__(256) void expand_kernel(
    const float* __restrict__ att, float* __restrict__ out)
{
    int e4 = blockIdx.x * 256 + threadIdx.x;
    int x4 = e4 & 31;
    int y  = (e4 >> 5) & (H_ - 1);
    int c  = (e4 >> 12) & (C_ - 1);
    int b  = (e4 >> 20) & 1;
    float4 v = *(const float4*)(att + ((size_t)(b*G_ + (c & 3)) * HW_) + y*W_ + x4*4);
    *(float4*)(out + ((size_t)(b*C_ + c) * HW_) + y*W_ + x4*4) = v;
}

// ---------------------------------------------------------------------------
extern "C" void kernel_launch(void* const* d_in, const int* in_sizes, int n_in,
                              void* d_out, int out_size, void* d_ws, size_t ws_size,
                              hipStream_t stream)
{
    (void)in_sizes; (void)n_in; (void)out_size;
    const float* x      = (const float*)d_in[0];
    const float* offset = (const float*)d_in[1];
    const float* W0     = (const float*)d_in[2];
    const float* b0     = (const float*)d_in[3];
    const float* gamma  = (const float*)d_in[4];
    const float* beta   = (const float*)d_in[5];
    const float* rmean  = (const float*)d_in[6];
    const float* rvar   = (const float*)d_in[7];
    const float* W1     = (const float*)d_in[8];
    const float* b1     = (const float*)d_in[9];
    float* out = (float*)d_out;

    const size_t xT_elems = (size_t)B_ * C_ * HW_;
    const size_t need_fused = (xT_elems + G_*C_ + G_ + 64) * sizeof(float);

    if (ws_size >= need_fused) {
        float* xT   = (float*)d_ws;
        float* Weff = xT + xT_elems;
        float* beff = Weff + G_ * C_;
        transpose_kernel<<<dim3(HW_/128, C_/32, B_ + 1), dim3(256), 0, stream>>>(
            x, xT, W0, b0, gamma, beta, rmean, rvar, W1, b1, Weff, beff);
        main_kernel<1><<<dim3(NBLK), dim3(512), 0, stream>>>(
            xT, offset, Weff, beff, out);
    } else {
        float* xT   = out;
        float* att  = (float*)d_ws;
        float* Weff = att + (size_t)B_ * G_ * HW_;
        float* beff = Weff + G_ * C_;
        transpose_kernel<<<dim3(HW_/128, C_/32, B_ + 1), dim3(256), 0, stream>>>(
            x, xT, W0, b0, gamma, beta, rmean, rvar, W1, b1, Weff, beff);
        main_kernel<0><<<dim3(NBLK), dim3(512), 0, stream>>>(
            xT, offset, Weff, beff, att);
        expand_kernel<<<dim3((B_*C_*HW_/4) / 256), dim3(256), 0, stream>>>(att, out);
    }
}